// Round 1
// 401.404 us; speedup vs baseline: 1.1525x; 1.1525x over previous
//
#include <hip/hip_runtime.h>

typedef _Float16 half8 __attribute__((ext_vector_type(8)));
typedef _Float16 half4t __attribute__((ext_vector_type(4)));
typedef _Float16 half2t __attribute__((ext_vector_type(2)));
typedef float float4t __attribute__((ext_vector_type(4)));

#define BATCH 32
#define CIN 64
#define HIN 128
#define WIN 128
#define COUT 128
#define HOUT 126
#define WOUT 126
#define YSTR 128   // padded pixel stride of fp16 y intermediate
#define HP 63
#define WP 63
#define NGROUPS 16
#define CPG 8
#define EPSV 1e-5f

// wT[pos][cout][cin] fp16, pos = kh*3+kw
__global__ __launch_bounds__(256) void wt_kernel(const float* __restrict__ w,
                                                 _Float16* __restrict__ wT) {
    int idx = blockIdx.x * 256 + threadIdx.x;
    if (idx >= 9 * COUT * CIN) return;
    int cin = idx & 63;
    int t = idx >> 6;
    int cout = t & 127;
    int pos = t >> 7;
    wT[idx] = (_Float16)w[(cout * CIN + cin) * 9 + pos];
}

// LDS layout: row R = r*130+col (390 rows), 64 cins per row = 128B.
// XOR swizzle: 16B chunk index (cin>>3) ^ (R&7). 49,920 B -> 3 blocks/CU.
// Reads: chunk = q + 4*ch, half8; n advances R by 16 (R&7 invariant) -> +2048B imm offsets.
__global__ __launch_bounds__(256, 3) void conv_mfma_kernel(
    const float* __restrict__ x, const _Float16* __restrict__ wT,
    const float* __restrict__ bias, _Float16* __restrict__ yh,
    float* __restrict__ stats)
{
    __shared__ __align__(16) _Float16 xs[3 * 130 * 64];

    const int tid = threadIdx.x;
    // XCD-chunked remap: XCD k gets contiguous work range -> 3 oy-adjacent blocks
    // sharing x rows hit the same per-XCD L2. 4032 = 8 * 504 (bijective).
    int f = blockIdx.y * 126 + blockIdx.x;
    int w = (f & 7) * 504 + (f >> 3);
    const int oy = w % 126;
    const int b  = w / 126;

    // ---- stage xs[R][cin] = fp16(x[b][cin][oy+r][col]), swizzled ----
    {
        const int cp   = tid & 31;        // cin pair -> cins {2cp, 2cp+1}
        const int seg  = tid >> 5;        // col segment of 16
        const int c0   = 2 * cp;
        const int chk  = cp >> 2;         // 16B chunk containing this cin pair
        const int wsub = (cp & 3) << 1;   // element offset within chunk
        const float* xb = x + (size_t)b * CIN * (HIN * WIN);
        for (int i = 0; i < 12; i++) {
            int r = i >> 2;
            int col4 = seg * 16 + (i & 3) * 4;
            const float* p0 = xb + ((size_t)c0 * HIN + (oy + r)) * WIN + col4;
            const float* p1 = p0 + (size_t)HIN * WIN;
            float4t va = *(const float4t*)p0;
            float4t vb = *(const float4t*)p1;
            int Rb = r * 130 + col4;
#pragma unroll
            for (int j = 0; j < 4; j++) {
                int R = Rb + j;
                half2t hv = { (_Float16)va[j], (_Float16)vb[j] };
                *(half2t*)&xs[(R << 6) + ((chk ^ (R & 7)) << 3) + wsub] = hv;
            }
        }
        // zero pad cols 128,129 (read by pixels >=126; stored to y pad, never consumed)
        if (tid < 192) {
            int cpz = tid & 31;
            int R = (tid >> 6) * 130 + 128 + ((tid >> 5) & 1);
            half2t z = { (_Float16)0.f, (_Float16)0.f };
            *(half2t*)&xs[(R << 6) + (((cpz >> 2) ^ (R & 7)) << 3) + ((cpz & 3) << 1)] = z;
        }
    }
    __syncthreads();

    const int lane = tid & 63;
    const int wv   = tid >> 6;
    const int m    = lane & 15;
    const int q    = lane >> 4;
    const int cout0 = wv * 32;

    float4t acc[2][8];
#pragma unroll
    for (int s = 0; s < 2; s++)
#pragma unroll
        for (int n = 0; n < 8; n++)
            acc[s][n] = (float4t){0.f, 0.f, 0.f, 0.f};

    // K-loop: 9 (kh,kw) x 2 cin-halves. Weights (B operand) prefetched from L2-hot wT.
    // OPERAND SWAP vs previous version: A = x-fragment (rows=pixels), B = weights
    // (cols=couts) => D lane (q,m): pixels n*16+q*4+reg for cout cout0+sub*16+m.
    const _Float16* ab0 = wT + (size_t)(cout0 + m) * CIN + q * 8;
    half8 a0 = *(const half8*)(ab0);
    half8 a1 = *(const half8*)(ab0 + 16 * CIN);

    for (int kk = 0; kk < 18; kk++) {
        int pos = kk >> 1, ch = kk & 1;
        int kh = (pos > 2) + (pos > 5);
        int kw = pos - kh * 3;
        int R0 = kh * 130 + m + kw;
        const _Float16* bb = &xs[(R0 << 6) + (((q + 4 * ch) ^ (R0 & 7)) << 3)];

        half8 na0 = a0, na1 = a1;
        if (kk < 17) {
            int nk = kk + 1, npos = nk >> 1, nch = nk & 1;
            const _Float16* ab = wT + ((size_t)(npos * COUT + cout0 + m)) * CIN + q * 8 + nch * 32;
            na0 = *(const half8*)ab;
            na1 = *(const half8*)(ab + 16 * CIN);
        }
#pragma unroll
        for (int n = 0; n < 8; n++) {
            half8 bf = *(const half8*)(bb + n * 1024);   // R += 16 per n -> +2048B
            acc[0][n] = __builtin_amdgcn_mfma_f32_16x16x32_f16(bf, a0, acc[0][n], 0, 0, 0);
            acc[1][n] = __builtin_amdgcn_mfma_f32_16x16x32_f16(bf, a1, acc[1][n], 0, 0, 0);
        }
        a0 = na0; a1 = na1;
    }

    // ---- epilogue: bias, packed fp16 stores (8B/lane), per-group stats ----
#pragma unroll
    for (int sub = 0; sub < 2; sub++) {
        const int c = cout0 + sub * 16 + m;
        const float bv = bias[c];
        _Float16* yrow = yh + (((size_t)b * COUT + c) * HOUT + oy) * YSTR;
        float sv = 0.f, ssv = 0.f;
#pragma unroll
        for (int n = 0; n < 8; n++) {
            int pix0 = n * 16 + q * 4;
            float v0 = acc[sub][n][0] + bv;
            float v1 = acc[sub][n][1] + bv;
            float v2 = acc[sub][n][2] + bv;
            float v3 = acc[sub][n][3] + bv;
            // pix0 <= 124, so pix0/pix0+1 always valid; +2/+3 invalid only at n==7,q==3
            sv  += v0 + v1;
            ssv += v0 * v0 + v1 * v1;
            if (pix0 + 3 < WOUT) {
                sv  += v2 + v3;
                ssv += v2 * v2 + v3 * v3;
            }
            half4t hv = { (_Float16)v0, (_Float16)v1, (_Float16)v2, (_Float16)v3 };
            *(half4t*)(yrow + pix0) = hv;   // 8B store, pad cols 126/127 hold garbage
        }
        // group = f(lane bit 3); reduce over lane bits 0,1,2,4,5
        sv  += __shfl_xor(sv, 1);   ssv += __shfl_xor(ssv, 1);
        sv  += __shfl_xor(sv, 2);   ssv += __shfl_xor(ssv, 2);
        sv  += __shfl_xor(sv, 4);   ssv += __shfl_xor(ssv, 4);
        sv  += __shfl_xor(sv, 16);  ssv += __shfl_xor(ssv, 16);
        sv  += __shfl_xor(sv, 32);  ssv += __shfl_xor(ssv, 32);
        if ((lane & 55) == 0) {     // lanes 0 and 8
            int g = (cout0 >> 3) + sub * 2 + ((lane >> 3) & 1);
            atomicAdd(&stats[(b * NGROUPS + g) * 2 + 0], sv);
            atomicAdd(&stats[(b * NGROUPS + g) * 2 + 1], ssv);
        }
    }
}

// idx bit-decode over padded 64x64 grid: pure shifts, no div/mod chains.
__global__ __launch_bounds__(256) void norm_pool_kernel(
    const _Float16* __restrict__ yh, const float* __restrict__ stats,
    const float* __restrict__ gnw, const float* __restrict__ gnb,
    const float* __restrict__ scale, float* __restrict__ out)
{
    int idx = blockIdx.x * 256 + threadIdx.x;
    int wp = idx & 63;
    int hp = (idx >> 6) & 63;
    if (wp >= WP || hp >= HP) return;
    int c  = (idx >> 12) & 127;
    int b  = idx >> 19;

    const float N = (float)(CPG * HOUT * WOUT);
    int g = c >> 3;
    float sum   = stats[(b * NGROUPS + g) * 2 + 0];
    float sumsq = stats[(b * NGROUPS + g) * 2 + 1];
    float mean = sum / N;
    float var  = sumsq / N - mean * mean;
    float rstd = rsqrtf(var + EPSV);

    float gw = gnw[c] * rstd;
    float A  = gw * scale[c];
    float B2 = (gnb[c] - mean * gw) * scale[c];

    const _Float16* yp = yh + ((((size_t)b * COUT + c) * HOUT + hp * 2) << 7) + wp * 2;
    half2t r0 = *(const half2t*)yp;
    half2t r1 = *(const half2t*)(yp + YSTR);
    float v0 = fmaf((float)r0[0], A, B2);
    float v1 = fmaf((float)r0[1], A, B2);
    float v2 = fmaf((float)r1[0], A, B2);
    float v3 = fmaf((float)r1[1], A, B2);
    float mx = fmaxf(fmaxf(v0, v1), fmaxf(v2, v3));
    out[(((size_t)b * COUT + c) * HP + hp) * WP + wp] = fminf(fmaxf(mx, 0.0f), 1.0f);
}

extern "C" void kernel_launch(void* const* d_in, const int* in_sizes, int n_in,
                              void* d_out, int out_size, void* d_ws, size_t ws_size,
                              hipStream_t stream) {
    const float* x      = (const float*)d_in[0];
    const float* conv_w = (const float*)d_in[1];
    const float* conv_b = (const float*)d_in[2];
    const float* gnw    = (const float*)d_in[3];
    const float* gnb    = (const float*)d_in[4];
    const float* scale  = (const float*)d_in[5];
    float* out = (float*)d_out;

    const size_t y_bytes = (size_t)BATCH * COUT * HOUT * YSTR * sizeof(_Float16); // 132 MB
    _Float16* yh = (_Float16*)d_ws;
    float* stats = (float*)((char*)d_ws + y_bytes);
    _Float16* wT = (_Float16*)((char*)d_ws + y_bytes + 4096);

    hipMemsetAsync(stats, 0, BATCH * NGROUPS * 2 * sizeof(float), stream);

    wt_kernel<<<(9 * COUT * CIN + 255) / 256, 256, 0, stream>>>(conv_w, wT);

    dim3 grid(HOUT, BATCH);
    conv_mfma_kernel<<<grid, 256, 0, stream>>>(x, wT, conv_b, yh, stats);

    norm_pool_kernel<<<(BATCH * COUT * 64 * 64) / 256, 256, 0, stream>>>(
        yh, stats, gnw, gnb, scale, out);
}

// Round 2
// 385.105 us; speedup vs baseline: 1.2013x; 1.0423x over previous
//
#include <hip/hip_runtime.h>

typedef _Float16 half8 __attribute__((ext_vector_type(8)));
typedef _Float16 half4t __attribute__((ext_vector_type(4)));
typedef _Float16 half2t __attribute__((ext_vector_type(2)));
typedef float float4t __attribute__((ext_vector_type(4)));
typedef float float4u __attribute__((ext_vector_type(4), aligned(4)));

#define BATCH 32
#define CIN 64
#define HIN 128
#define WIN 128
#define COUT 128
#define HOUT 126
#define WOUT 126
#define YSTR 128   // padded pixel stride of fp16 y intermediate
#define HP 63
#define WP 63
#define NGROUPS 16
#define CPG 8
#define EPSV 1e-5f

// xp row: 130 cols x 64 cins fp16 = 16640 B; elem stride per row = 8320
#define XP_ROW 8320

// wT[pos][cout][cin] fp16, pos = kh*3+kw
__global__ __launch_bounds__(256) void wt_kernel(const float* __restrict__ w,
                                                 _Float16* __restrict__ wT) {
    int idx = blockIdx.x * 256 + threadIdx.x;
    if (idx >= 9 * COUT * CIN) return;
    int cin = idx & 63;
    int t = idx >> 6;
    int cout = t & 127;
    int pos = t >> 7;
    wT[idx] = (_Float16)w[(cout * CIN + cin) * 9 + pos];
}

// Repack x NCHW fp32 -> xp[b][grow][col(130)][cin(64)] fp16, PRE-SWIZZLED:
// logical cin-chunk chk (8 cins) of (grow,col) stored at slot chk ^ ((2*grow+col)&7).
// Cols 128,129 zeroed (pad). One block per (b,grow); LDS transpose for coalescing.
__global__ __launch_bounds__(256) void repack_kernel(const float* __restrict__ x,
                                                     _Float16* __restrict__ xp) {
    __shared__ _Float16 lt[128 * 66];   // [col][cin], stride 66 to break banks
    const int tid = threadIdx.x;
    const int grow = blockIdx.x;
    const int b = blockIdx.y;

    // read coalesced: 32 lanes cover one cin's full 512B row
    const int c0 = tid >> 5;
    const int col0 = (tid & 31) * 4;
#pragma unroll
    for (int i = 0; i < 8; i++) {
        int cin = c0 + 8 * i;
        float4t v = *(const float4t*)(x + (((size_t)b * CIN + cin) * HIN + grow) * WIN + col0);
#pragma unroll
        for (int j = 0; j < 4; j++)
            lt[(col0 + j) * 66 + cin] = (_Float16)v[j];
    }
    __syncthreads();

    _Float16* xpb = xp + ((size_t)b * HIN + grow) * XP_ROW;
#pragma unroll
    for (int k = 0; k < 4; k++) {
        int cidx = tid + 256 * k;        // 0..1023 -> (col 0..127, chk 0..7)
        int col = cidx >> 3, chk = cidx & 7;
        half8 v = *(const half8*)&lt[col * 66 + chk * 8];
        int slot = chk ^ ((2 * grow + col) & 7);
        *(half8*)(xpb + col * 64 + slot * 8) = v;
    }
    if (tid < 16) {                      // pad cols 128,129 = zeros
        int col = 128 + (tid >> 3), chk = tid & 7;
        int slot = chk ^ ((2 * grow + col) & 7);
        half8 z;
#pragma unroll
        for (int j = 0; j < 8; j++) z[j] = (_Float16)0.f;
        *(half8*)(xpb + col * 64 + slot * 8) = z;
    }
}

// Conv: stage = linear 50KB copy via global_load_lds (xp pre-swizzled, LDS linear).
// K-loop swizzle key recomputed from global row (2*(oy+kh)+m+kw)&7.
__global__ __launch_bounds__(256, 3) void conv_mfma_kernel(
    const _Float16* __restrict__ xp, const _Float16* __restrict__ wT,
    const float* __restrict__ bias, _Float16* __restrict__ yh,
    float* __restrict__ stats)
{
    __shared__ __align__(16) _Float16 xs[25088];   // 50176 B (3 rows*130*64 + 256B slack)

    const int tid = threadIdx.x;
    // XCD-chunked remap (bijective: 4032 = 8*504)
    int f = blockIdx.y * 126 + blockIdx.x;
    int w = (f & 7) * 504 + (f >> 3);
    const int oy = w % 126;
    const int b  = w / 126;

    const int lane = tid & 63;
    const int wv   = tid >> 6;

    // ---- stage: contiguous 49920B (+256 slack) from xp -> LDS, 16B/lane ----
    {
        const char* src = (const char*)(xp + (size_t)(b * HIN + oy) * XP_ROW);
        const int wb = wv * 1024;
#pragma unroll
        for (int k = 0; k < 12; k++) {
            __builtin_amdgcn_global_load_lds(
                (const __attribute__((address_space(1))) void*)(src + k * 4096 + wb + lane * 16),
                (__attribute__((address_space(3))) void*)((char*)xs + k * 4096 + wb),
                16, 0, 0);
        }
        if (wv == 0) {
            __builtin_amdgcn_global_load_lds(
                (const __attribute__((address_space(1))) void*)(src + 49152 + lane * 16),
                (__attribute__((address_space(3))) void*)((char*)xs + 49152),
                16, 0, 0);
        }
    }
    __syncthreads();

    const int m    = lane & 15;
    const int q    = lane >> 4;
    const int cout0 = (tid >> 6) * 32;

    float4t acc[2][8];
#pragma unroll
    for (int s = 0; s < 2; s++)
#pragma unroll
        for (int n = 0; n < 8; n++)
            acc[s][n] = (float4t){0.f, 0.f, 0.f, 0.f};

    // A = weights (B-operand of mfma is x): D lane (q,m): pixels n*16+q*4+reg, cout cout0+sub*16+m
    const _Float16* ab0 = wT + (size_t)(cout0 + m) * CIN + q * 8;
    half8 a0 = *(const half8*)(ab0);
    half8 a1 = *(const half8*)(ab0 + 16 * CIN);

    for (int kk = 0; kk < 18; kk++) {
        int pos = kk >> 1, ch = kk & 1;
        int kh = (pos > 2) + (pos > 5);
        int kw = pos - kh * 3;
        int key = (2 * (oy + kh) + m + kw) & 7;
        const _Float16* bb = &xs[(kh * 130 + m + kw) * 64 + (((q + 4 * ch) ^ key) << 3)];

        half8 na0 = a0, na1 = a1;
        if (kk < 17) {
            int nk = kk + 1, npos = nk >> 1, nch = nk & 1;
            const _Float16* ab = wT + ((size_t)(npos * COUT + cout0 + m)) * CIN + q * 8 + nch * 32;
            na0 = *(const half8*)ab;
            na1 = *(const half8*)(ab + 16 * CIN);
        }
#pragma unroll
        for (int n = 0; n < 8; n++) {
            half8 bf = *(const half8*)(bb + n * 1024);   // col += 16 -> +2048B, key invariant
            acc[0][n] = __builtin_amdgcn_mfma_f32_16x16x32_f16(bf, a0, acc[0][n], 0, 0, 0);
            acc[1][n] = __builtin_amdgcn_mfma_f32_16x16x32_f16(bf, a1, acc[1][n], 0, 0, 0);
        }
        a0 = na0; a1 = na1;
    }

    // ---- epilogue: bias, packed fp16 stores, per-group stats ----
#pragma unroll
    for (int sub = 0; sub < 2; sub++) {
        const int c = cout0 + sub * 16 + m;
        const float bv = bias[c];
        _Float16* yrow = yh + (((size_t)b * COUT + c) * HOUT + oy) * YSTR;
        float sv = 0.f, ssv = 0.f;
#pragma unroll
        for (int n = 0; n < 8; n++) {
            int pix0 = n * 16 + q * 4;
            float v0 = acc[sub][n][0] + bv;
            float v1 = acc[sub][n][1] + bv;
            float v2 = acc[sub][n][2] + bv;
            float v3 = acc[sub][n][3] + bv;
            sv  += v0 + v1;
            ssv += v0 * v0 + v1 * v1;
            if (pix0 + 3 < WOUT) {
                sv  += v2 + v3;
                ssv += v2 * v2 + v3 * v3;
            }
            half4t hv = { (_Float16)v0, (_Float16)v1, (_Float16)v2, (_Float16)v3 };
            *(half4t*)(yrow + pix0) = hv;   // pad cols 126/127 garbage, never consumed
        }
        sv  += __shfl_xor(sv, 1);   ssv += __shfl_xor(ssv, 1);
        sv  += __shfl_xor(sv, 2);   ssv += __shfl_xor(ssv, 2);
        sv  += __shfl_xor(sv, 4);   ssv += __shfl_xor(ssv, 4);
        sv  += __shfl_xor(sv, 16);  ssv += __shfl_xor(ssv, 16);
        sv  += __shfl_xor(sv, 32);  ssv += __shfl_xor(ssv, 32);
        if ((lane & 55) == 0) {     // lanes 0 and 8
            int g = (cout0 >> 3) + sub * 2 + ((lane >> 3) & 1);
            atomicAdd(&stats[(b * NGROUPS + g) * 2 + 0], sv);
            atomicAdd(&stats[(b * NGROUPS + g) * 2 + 1], ssv);
        }
    }
}

// Vectorized: thread = 4 output pixels along wp; 2x half8 (16B) row loads.
// Block covers one (b, c, 16 hp rows). grid = 32*128*4.
__global__ __launch_bounds__(256) void norm_pool_kernel(
    const _Float16* __restrict__ yh, const float* __restrict__ stats,
    const float* __restrict__ gnw, const float* __restrict__ gnb,
    const float* __restrict__ scale, float* __restrict__ out)
{
    const int t  = threadIdx.x & 15;        // out cols 4t..4t+3
    const int hs = threadIdx.x >> 4;        // 0..15
    const int hblk = blockIdx.x & 3;
    const int c = (blockIdx.x >> 2) & 127;
    const int b = blockIdx.x >> 9;
    const int hp = hblk * 16 + hs;

    const float N = (float)(CPG * HOUT * WOUT);
    int g = c >> 3;
    float sum   = stats[(b * NGROUPS + g) * 2 + 0];
    float sumsq = stats[(b * NGROUPS + g) * 2 + 1];
    float mean = sum / N;
    float var  = sumsq / N - mean * mean;
    float rstd = rsqrtf(var + EPSV);

    float gw = gnw[c] * rstd;
    float A  = gw * scale[c];
    float B2 = (gnb[c] - mean * gw) * scale[c];

    if (hp >= HP) return;

    const _Float16* yp = yh + ((((size_t)b * COUT + c) * HOUT + hp * 2) << 7) + t * 8;
    half8 r0 = *(const half8*)yp;
    half8 r1 = *(const half8*)(yp + YSTR);

    float o[4];
#pragma unroll
    for (int j = 0; j < 4; j++) {
        float v0 = fmaf((float)r0[2 * j],     A, B2);
        float v1 = fmaf((float)r0[2 * j + 1], A, B2);
        float v2 = fmaf((float)r1[2 * j],     A, B2);
        float v3 = fmaf((float)r1[2 * j + 1], A, B2);
        float mx = fmaxf(fmaxf(v0, v1), fmaxf(v2, v3));
        o[j] = fminf(fmaxf(mx, 0.0f), 1.0f);
    }

    float* op = out + (((size_t)b * COUT + c) * HP + hp) * WP + t * 4;
    if (t < 15) {
        *(float4u*)op = (float4u){o[0], o[1], o[2], o[3]};
    } else {          // out cols 60,61,62 valid; 63 doesn't exist
        op[0] = o[0]; op[1] = o[1]; op[2] = o[2];
    }
}

extern "C" void kernel_launch(void* const* d_in, const int* in_sizes, int n_in,
                              void* d_out, int out_size, void* d_ws, size_t ws_size,
                              hipStream_t stream) {
    const float* x      = (const float*)d_in[0];
    const float* conv_w = (const float*)d_in[1];
    const float* conv_b = (const float*)d_in[2];
    const float* gnw    = (const float*)d_in[3];
    const float* gnb    = (const float*)d_in[4];
    const float* scale  = (const float*)d_in[5];
    float* out = (float*)d_out;

    const size_t y_bytes = (size_t)BATCH * COUT * HOUT * YSTR * sizeof(_Float16); // 132 MB
    _Float16* yh = (_Float16*)d_ws;
    float* stats = (float*)((char*)d_ws + y_bytes);                 // 4 KB reserved
    _Float16* wT = (_Float16*)((char*)d_ws + y_bytes + 4096);       // 147456 B
    _Float16* xp = (_Float16*)((char*)d_ws + y_bytes + 4096 + 147456); // 68.2 MB (+512B slack used)

    hipMemsetAsync(stats, 0, BATCH * NGROUPS * 2 * sizeof(float), stream);

    wt_kernel<<<(9 * COUT * CIN + 255) / 256, 256, 0, stream>>>(conv_w, wT);

    dim3 rgrid(HIN, BATCH);
    repack_kernel<<<rgrid, 256, 0, stream>>>(x, xp);

    dim3 grid(HOUT, BATCH);
    conv_mfma_kernel<<<grid, 256, 0, stream>>>(xp, wT, conv_b, yh, stats);

    norm_pool_kernel<<<BATCH * COUT * 4, 256, 0, stream>>>(
        yh, stats, gnw, gnb, scale, out);
}